// Round 17
// baseline (79.647 us; speedup 1.0000x reference)
//
#include <hip/hip_runtime.h>
#include <math.h>

#define DEVI __device__ __forceinline__

static constexpr float KD[10] = {
  0.027333068345077982f,  0.029519490925774643f, -0.039134249302383094f,
  0.1993975339773936f,    0.7234076904024206f,    0.6339789634582119f,
  0.01660210576452232f,  -0.17532808990845047f,  -0.021101834024758855f,
  0.019538882735286728f};

// ---------- workspace layout (float offsets) ----------
#define CE_OFF     0         // 105000 floats
#define PH_OFF     105056    // exp-hist partials: nb x 256 uints per scale
#define PH1_REL    80128     // NB3*256
#define PH2_REL    100352    // + NB4*256  (total 110592)
#define MH_OFF     215648    // m8-hist partials: 3 x 96 x 256 uints
#define BS_OFF     289376    // m8 bin value-sum partials: 3 x 96 x 256 floats
#define SLOTGT_OFF 363104    // 3 x 96 floats
#define STATE_OFF  363392    // 3 x 8 words
#define SLOT2_OFF  363424    // 3 x 96 floats
#define TICKET_OFF 363712    // 3 uints
#define CBUF_OFF   363728    // 3 x CAPC floats
#define CAPC       49152
#define PART_OFF   511200    // 3 x PART_STRIDE floats
#define PART_STRIDE 7680     // >= 4*NB3*6 = 7512

#define NB3 313              // ceil(80000/256)  (128 thr x 2 px)
#define NB4 79               // ceil(20000/256)
#define NB5 40               // ceil(5000/128)   (1 px/thread, HW odd)
#define NBR 96

DEVI float wave_sum(float v) {
#pragma unroll
  for (int d = 32; d; d >>= 1) v += __shfl_down(v, d);
  return v;
}

DEVI float block_sum(float v, float* sh) {
  int lane = threadIdx.x & 63, wid = threadIdx.x >> 6;
  v = wave_sum(v);
  if (lane == 0) sh[wid] = v;
  __syncthreads();
  if (threadIdx.x == 0) {
    float s = 0.f;
    int nw = blockDim.x >> 6;
    for (int w = 0; w < nw; ++w) s += sh[w];
    sh[0] = s;
  }
  __syncthreads();
  float r = sh[0];
  __syncthreads();
  return r;
}

DEVI int suffix_scan_256(int v, int* sh) {
  int t = threadIdx.x;
  sh[t] = v;
  __syncthreads();
#pragma unroll
  for (int off = 1; off < 256; off <<= 1) {
    int x = (t + off < 256) ? sh[t + off] : 0;
    __syncthreads();
    sh[t] += x;
    __syncthreads();
  }
  return sh[t];
}

DEVI float sl1(float v) { float a = fabsf(v); return (a < 1.f) ? 0.5f * v * v : a - 0.5f; }

DEVI float ce2cls(float la, float lb, float tgt) {
  float m = fmaxf(la, lb);
  float lse = m + __logf(__expf(la - m) + __expf(lb - m));
  return lse - ((tgt > 0.5f) ? lb : la);
}

// ---- scalar half-recon (scale 5) ----
template <int H>
DEVI float recon_half(const float* __restrict__ rb, const float* __restrict__ gb,
                      int rc0, int gc0, size_t HW, float off) {
  constexpr int CLO  = (H == 0) ? 0 : 6;
  constexpr int A1LO = (H == 0) ? 0 : 12;
  constexpr int J2LO = (H == 0) ? 0 : 25;
  float c[14];
#pragma unroll
  for (int i = 0; i < 14; ++i)
    c[i] = rb[(size_t)(rc0 + CLO + i) * HW] - gb[(size_t)(gc0 + CLO + i) * HW];
  float a1[19];
#pragma unroll
  for (int k = 0; k < 19; ++k) {
    int o1 = A1LO + k, b = (o1 >> 1) - CLO;
    if (o1 & 1)
      a1[k] = KD[0]*c[b] + KD[2]*c[b+1] + KD[4]*c[b+2] + KD[6]*c[b+3] + KD[8]*c[b+4];
    else
      a1[k] = KD[1]*c[b] + KD[3]*c[b+1] + KD[5]*c[b+2] + KD[7]*c[b+3] + KD[9]*c[b+4];
  }
  float w0=0.f,w1=0.f,w2=0.f,w3=0.f,w4=0.f, acc=0.f;
#pragma unroll
  for (int k = 0; k < 29; ++k) {
    int j2 = J2LO + k, b = (j2 >> 1) - A1LO;
    float a2v;
    if (j2 & 1)
      a2v = KD[0]*a1[b] + KD[2]*a1[b+1] + KD[4]*a1[b+2] + KD[6]*a1[b+3] + KD[8]*a1[b+4];
    else
      a2v = KD[1]*a1[b] + KD[3]*a1[b+1] + KD[5]*a1[b+2] + KD[7]*a1[b+3] + KD[9]*a1[b+4];
    w0=w1; w1=w2; w2=w3; w3=w4; w4=a2v;
    if (k >= 4) {
      acc += sl1(KD[1]*w0 + KD[3]*w1 + KD[5]*w2 + KD[7]*w3 + KD[9]*w4 + off);
      acc += sl1(KD[0]*w0 + KD[2]*w1 + KD[4]*w2 + KD[6]*w3 + KD[8]*w4 + off);
    }
  }
  return acc;
}

// ---- float2 dual-pixel half-recon (scales 3/4, HW even, hw even) ----
DEVI float2 tap2o(const float2* a, int b) {
  float2 r;
  r.x = KD[0]*a[b].x + KD[2]*a[b+1].x + KD[4]*a[b+2].x + KD[6]*a[b+3].x + KD[8]*a[b+4].x;
  r.y = KD[0]*a[b].y + KD[2]*a[b+1].y + KD[4]*a[b+2].y + KD[6]*a[b+3].y + KD[8]*a[b+4].y;
  return r;
}
DEVI float2 tap2e(const float2* a, int b) {
  float2 r;
  r.x = KD[1]*a[b].x + KD[3]*a[b+1].x + KD[5]*a[b+2].x + KD[7]*a[b+3].x + KD[9]*a[b+4].x;
  r.y = KD[1]*a[b].y + KD[3]*a[b+1].y + KD[5]*a[b+2].y + KD[7]*a[b+3].y + KD[9]*a[b+4].y;
  return r;
}
template <int H>
DEVI float2 recon2(const float* __restrict__ rb, const float* __restrict__ gb,
                   int rc0, int gc0, size_t HW, float2 off) {
  constexpr int CLO  = (H == 0) ? 0 : 6;
  constexpr int A1LO = (H == 0) ? 0 : 12;
  constexpr int J2LO = (H == 0) ? 0 : 25;
  float2 c[14];
#pragma unroll
  for (int i = 0; i < 14; ++i) {
    float2 rv = *(const float2*)(rb + (size_t)(rc0 + CLO + i) * HW);
    float2 gv = *(const float2*)(gb + (size_t)(gc0 + CLO + i) * HW);
    c[i].x = rv.x - gv.x; c[i].y = rv.y - gv.y;
  }
  float2 a1[19];
#pragma unroll
  for (int k = 0; k < 19; ++k) {
    int o1 = A1LO + k, b = (o1 >> 1) - CLO;
    a1[k] = (o1 & 1) ? tap2o(c, b) : tap2e(c, b);
  }
  float2 w0={0,0},w1={0,0},w2={0,0},w3={0,0},w4={0,0};
  float2 acc={0,0};
#pragma unroll
  for (int k = 0; k < 29; ++k) {
    int j2 = J2LO + k, b = (j2 >> 1) - A1LO;
    float2 a2v = (j2 & 1) ? tap2o(a1, b) : tap2e(a1, b);
    w0=w1; w1=w2; w2=w3; w3=w4; w4=a2v;
    if (k >= 4) {
      float vex = KD[1]*w0.x + KD[3]*w1.x + KD[5]*w2.x + KD[7]*w3.x + KD[9]*w4.x + off.x;
      float vey = KD[1]*w0.y + KD[3]*w1.y + KD[5]*w2.y + KD[7]*w3.y + KD[9]*w4.y + off.y;
      float vox = KD[0]*w0.x + KD[2]*w1.x + KD[4]*w2.x + KD[6]*w3.x + KD[8]*w4.x + off.x;
      float voy = KD[0]*w0.y + KD[2]*w1.y + KD[4]*w2.y + KD[6]*w3.y + KD[8]*w4.y + off.y;
      acc.x += sl1(vex) + sl1(vox);
      acc.y += sl1(vey) + sl1(voy);
    }
  }
  return acc;
}

// 128-thread blocks (2 waves), 2 px/thread on scales 3/4, 1 px on scale 5.
// blockIdx.y in [0,4): axis = y>>1, half = y&1. CE/hist only in y==0.
__global__ void __launch_bounds__(128, 3)
pixel_kernel(const float* __restrict__ cls3, const float* __restrict__ reg3, const float* __restrict__ gt3,
             const float* __restrict__ cls4, const float* __restrict__ reg4, const float* __restrict__ gt4,
             const float* __restrict__ cls5, const float* __restrict__ reg5, const float* __restrict__ gt5,
             float* __restrict__ ws, float* __restrict__ out) {
  int bx = blockIdx.x, y = blockIdx.y, t = threadIdx.x;
  int axis = y >> 1, half = y & 1;
  const float *cls, *reg, *gt;
  int M, HW, ceOff, partBase, phRel, nb, lbx, two;
  if (bx < NB3) {
    cls = cls3; reg = reg3; gt = gt3; M = 80000; HW = 10000;
    ceOff = 0; partBase = PART_OFF; phRel = 0; nb = NB3; lbx = bx; two = 1;
  } else if (bx < NB3 + NB4) {
    cls = cls4; reg = reg4; gt = gt4; M = 20000; HW = 2500;
    ceOff = 80000; partBase = PART_OFF + PART_STRIDE; phRel = PH1_REL; nb = NB4; lbx = bx - NB3; two = 1;
  } else {
    cls = cls5; reg = reg5; gt = gt5; M = 5000; HW = 625;
    ceOff = 100000; partBase = PART_OFF + 2 * PART_STRIDE; phRel = PH2_REL; nb = NB5; lbx = bx - NB3 - NB4; two = 0;
  }
  float* ceArr = ws + ceOff;
  unsigned* ph = (unsigned*)(ws + PH_OFF) + phRel;

  if (bx == 0 && y == 0 && t < 3) out[t] = 0.f;

  __shared__ unsigned hlds[256];
  __shared__ float shp[2][6];
  hlds[t] = 0u; hlds[t + 128] = 0u;
  __syncthreads();

  float cnt_pos = 0.f, cnt_neg = 0.f, s_ce_pos = 0.f, s_tcl_ttm = 0.f, s_tcl_negm = 0.f;
  float s_ttm_pp = 0.f;
  int rc0 = axis ? 21 : 0;
  int gc0 = axis ? 24 : 3;

  if (two) {
    int p0 = (lbx * 128 + t) * 2;
    if (p0 < M) {
      int n = p0 / HW, hw = p0 % HW;      // hw even, pair stays in-row (HW even)
      const float* gb = gt  + (size_t)n * 45 * HW + hw;
      const float* rb = reg + (size_t)n * 42 * HW + hw;
      float2 trv = *(const float2*)(gb);
      float2 tnv = *(const float2*)(gb + 2 * (size_t)HW);
      float2 ttm; ttm.x = trv.x * tnv.x; ttm.y = trv.y * tnv.y;

      if (y == 0) {
        const float* cb = cls + (size_t)n * 4 * HW + hw;
        float2 l0 = *(const float2*)(cb);
        float2 l1 = *(const float2*)(cb + (size_t)HW);
        float2 l2 = *(const float2*)(cb + 2 * (size_t)HW);
        float2 l3 = *(const float2*)(cb + 3 * (size_t)HW);
        float2 tcl = *(const float2*)(gb + (size_t)HW);
        float cex = ce2cls(l0.x, l1.x, trv.x), cey = ce2cls(l0.y, l1.y, trv.y);
        float ctx = ce2cls(l2.x, l3.x, tcl.x), cty = ce2cls(l2.y, l3.y, tcl.y);
        bool posx = ttm.x > 0.f, posy = ttm.y > 0.f;
        bool negx = ((1.f - trv.x) * tnv.x) > 0.f, negy = ((1.f - trv.y) * tnv.y) > 0.f;
        float cvx = negx ? cex : 0.f, cvy = negy ? cey : 0.f;
        float2 cev; cev.x = cvx; cev.y = cvy;
        *(float2*)(ceArr + p0) = cev;
        if (negx) atomicAdd(&hlds[__float_as_uint(cvx) >> 23], 1u);
        if (negy) atomicAdd(&hlds[__float_as_uint(cvy) >> 23], 1u);
        cnt_pos = (posx ? 1.f : 0.f) + (posy ? 1.f : 0.f);
        cnt_neg = (negx ? 1.f : 0.f) + (negy ? 1.f : 0.f);
        s_ce_pos = (posx ? cex : 0.f) + (posy ? cey : 0.f);
        s_tcl_ttm = ctx * ttm.x + cty * ttm.y;
        s_tcl_negm = ctx * (1.f - ttm.x) + cty * (1.f - ttm.y);
      }

      float2 rcv = *(const float2*)(rb + (size_t)(rc0 + 20) * HW);
      float2 gcv = *(const float2*)(gb + (size_t)(gc0 + 20) * HW);
      float2 dc; dc.x = rcv.x - gcv.x; dc.y = rcv.y - gcv.y;
      float2 pp = half ? recon2<1>(rb, gb, rc0, gc0, (size_t)HW, dc)
                       : recon2<0>(rb, gb, rc0, gc0, (size_t)HW, dc);
      s_ttm_pp = ttm.x * pp.x + ttm.y * pp.y;
    }
  } else {
    int p = lbx * 128 + t;
    if (p < M) {
      int n = p / HW, hw = p % HW;
      const float* gb = gt  + (size_t)n * 45 * HW + hw;
      const float* rb = reg + (size_t)n * 42 * HW + hw;
      float tr = gb[0], train = gb[2 * (size_t)HW];
      float ttm = tr * train;
      if (y == 0) {
        const float* cb = cls + (size_t)n * 4 * HW + hw;
        float ce_tr = ce2cls(cb[0], cb[(size_t)HW], tr);
        float ce_tcl = ce2cls(cb[2 * (size_t)HW], cb[3 * (size_t)HW], gb[(size_t)HW]);
        bool pos = ttm > 0.f;
        bool neg = ((1.f - tr) * train) > 0.f;
        float cev = neg ? ce_tr : 0.f;
        ceArr[p] = cev;
        if (neg) atomicAdd(&hlds[__float_as_uint(cev) >> 23], 1u);
        cnt_pos = pos ? 1.f : 0.f;
        cnt_neg = neg ? 1.f : 0.f;
        s_ce_pos = pos ? ce_tr : 0.f;
        s_tcl_ttm = ce_tcl * ttm;
        s_tcl_negm = ce_tcl * (1.f - ttm);
      }
      float dc = rb[(size_t)(rc0 + 20) * HW] - gb[(size_t)(gc0 + 20) * HW];
      float pp = half ? recon_half<1>(rb, gb, rc0, gc0, (size_t)HW, dc)
                      : recon_half<0>(rb, gb, rc0, gc0, (size_t)HW, dc);
      s_ttm_pp = ttm * pp;
    }
  }

  int lane = t & 63, wid = t >> 6;
  cnt_pos = wave_sum(cnt_pos);
  cnt_neg = wave_sum(cnt_neg);
  s_ce_pos = wave_sum(s_ce_pos);
  s_tcl_ttm = wave_sum(s_tcl_ttm);
  s_tcl_negm = wave_sum(s_tcl_negm);
  s_ttm_pp = wave_sum(s_ttm_pp);
  if (lane == 0) {
    shp[wid][0] = cnt_pos; shp[wid][1] = cnt_neg; shp[wid][2] = s_ce_pos;
    shp[wid][3] = s_tcl_ttm; shp[wid][4] = s_tcl_negm; shp[wid][5] = s_ttm_pp;
  }
  __syncthreads();
  if (t < 6) {
    float s = shp[0][t] + shp[1][t];
    ws[partBase + (size_t)(y * nb + lbx) * 6 + t] = s;
  }
  if (y == 0) {
    ph[(size_t)lbx * 256 + t] = hlds[t];
    ph[(size_t)lbx * 256 + t + 128] = hlds[t + 128];
  }
}

// grid-wide refine with merged selA (atomic-free PH sweep) + ticket reset.
__global__ void refine_kernel(float* __restrict__ ws) {
  int s = blockIdx.y, r = blockIdx.x, t = threadIdx.x;
  int M   = (s == 0) ? 80000 : (s == 1 ? 20000 : 5000);
  int off = (s == 0) ? 0     : (s == 1 ? 80000 : 100000);
  int nb0 = (s == 0) ? NB3   : (s == 1 ? NB4   : NB5);
  int phRel = (s == 0) ? 0 : (s == 1 ? PH1_REL : PH2_REL);
  int* st = (int*)(ws + STATE_OFF) + s * 8;

  if (r == 0 && t == 0) ((unsigned*)(ws + TICKET_OFF))[s] = 0u;

  __shared__ int sh[256];
  __shared__ int sel[2];
  __shared__ float red[4];
  __shared__ unsigned hW[4][256];
  __shared__ unsigned mhL[256];
  __shared__ float bsL[256];

  const float* part = ws + PART_OFF + s * PART_STRIDE;
  int npart = 4 * nb0;
  float a0 = 0.f, a1 = 0.f, a2 = 0.f, a3 = 0.f, a4 = 0.f, a5 = 0.f;
  for (int i = t; i < npart; i += 256) {
    const float* p6 = part + (size_t)i * 6;
    a0 += p6[0]; a1 += p6[1]; a2 += p6[2]; a3 += p6[3]; a4 += p6[4]; a5 += p6[5];
  }
  a0 = block_sum(a0, red);
  a1 = block_sum(a1, red);
  a2 = block_sum(a2, red);
  a3 = block_sum(a3, red);
  a4 = block_sum(a4, red);
  a5 = block_sum(a5, red);

  float cnt_pos = a0, cnt_negf = a1;
  int cnt_neg = (int)cnt_negf;
  float kf = (cnt_pos > 0.f) ? fminf(cnt_negf, floorf(3.f * cnt_pos)) : 100.f;
  int k_take = min((int)kf, cnt_neg);

  int ibin, rem;
  if (k_take >= cnt_neg) { ibin = -1; rem = 0; }
  else if (k_take <= 0)  { ibin = 256; rem = 0; }
  else {
    const uint4* ph4 = (const uint4*)((const unsigned*)(ws + PH_OFF) + phRel);
    unsigned c0 = 0u, c1 = 0u, c2 = 0u, c3 = 0u;
    int n4 = nb0 * 64;
    for (int i = t; i < n4; i += 256) {
      uint4 u = ph4[i];
      c0 += u.x; c1 += u.y; c2 += u.z; c3 += u.w;
    }
    int wid = t >> 6, b0 = (4 * t) & 255;
    hW[wid][b0 + 0] = c0; hW[wid][b0 + 1] = c1; hW[wid][b0 + 2] = c2; hW[wid][b0 + 3] = c3;
    __syncthreads();
    int h = (int)(hW[0][t] + hW[1][t] + hW[2][t] + hW[3][t]);
    int suf = suffix_scan_256(h, sh);
    int above = suf - h;
    if (suf >= k_take && above < k_take) { sel[0] = t; sel[1] = k_take - above; }
    __syncthreads();
    ibin = sel[0]; rem = sel[1];
    __syncthreads();
  }
  if (r == 0 && t == 0) {
    st[0] = ibin; st[1] = rem;
    float* stf = (float*)st;
    stf[2] = kf; stf[3] = a0; stf[4] = a2; stf[5] = a3; stf[6] = a4; stf[7] = a5;
  }

  mhL[t] = 0u; bsL[t] = 0.f;
  __syncthreads();
  const float* ce = ws + off;
  float sum = 0.f;
  for (int i = r * 256 + t; i < M; i += NBR * 256) {
    float v = ce[i];
    unsigned b = __float_as_uint(v);
    int e = (int)(b >> 23);
    if (e > ibin) sum += v;
    else if (e == ibin && rem > 0) {
      int m8 = (int)((b >> 15) & 255u);
      atomicAdd(&mhL[m8], 1u);
      atomicAdd(&bsL[m8], v);
    }
  }
  sum = block_sum(sum, red);
  if (t == 0) ws[SLOTGT_OFF + s * NBR + r] = sum;
  if (rem > 0) {
    ((unsigned*)(ws + MH_OFF))[((size_t)s * NBR + r) * 256 + t] = mhL[t];
    ws[BS_OFF + ((size_t)s * NBR + r) * 256 + t] = bsL[t];
  }
}

// grid-wide compact + LAST-BLOCK final (ticket; no polling). Each block:
// redundant jbin select, own-row gt2, prefix rank-write; then one atomicAdd
// on the scale's ticket — the 96th arrival assembles the losses.
__global__ void compactB_kernel(float* __restrict__ ws, float* __restrict__ out) {
  int s = blockIdx.y, r = blockIdx.x, t = threadIdx.x;
  int M   = (s == 0) ? 80000 : (s == 1 ? 20000 : 5000);
  int off = (s == 0) ? 0     : (s == 1 ? 80000 : 100000);
  const int* st = (const int*)(ws + STATE_OFF) + s * 8;
  const float* stf = (const float*)st;
  int ibin = st[0], rem = st[1];

  __shared__ int sh[256];
  __shared__ int sel[2];
  __shared__ float red[4];
  __shared__ unsigned hW[4][256];
  __shared__ int hist[256];
  __shared__ unsigned wcnt;
  __shared__ unsigned tickL;

  int jbin = 0, rem2 = 0, jcnt = 0;
  if (rem > 0) {
    const unsigned* mh = (const unsigned*)(ws + MH_OFF) + (size_t)s * NBR * 256;
    const uint4* mh4 = (const uint4*)mh;
    unsigned c0 = 0u, c1 = 0u, c2 = 0u, c3 = 0u;
    for (int i = t; i < NBR * 64; i += 256) {
      uint4 u = mh4[i];
      c0 += u.x; c1 += u.y; c2 += u.z; c3 += u.w;
    }
    int wid = t >> 6, b0 = (4 * t) & 255;
    hW[wid][b0 + 0] = c0; hW[wid][b0 + 1] = c1; hW[wid][b0 + 2] = c2; hW[wid][b0 + 3] = c3;
    __syncthreads();
    int h = (int)(hW[0][t] + hW[1][t] + hW[2][t] + hW[3][t]);
    int suf = suffix_scan_256(h, sh);
    int above = suf - h;
    if (suf >= rem && above < rem) { sel[0] = t; sel[1] = rem - above; }
    __syncthreads();
    jbin = sel[0]; rem2 = sel[1];
    jcnt = (int)(hW[0][jbin] + hW[1][jbin] + hW[2][jbin] + hW[3][jbin]);
    __syncthreads();

    // per-block gt2 from own bs row
    float v2 = ws[BS_OFF + ((size_t)s * NBR + r) * 256 + t];
    float gt2 = block_sum((t > jbin) ? v2 : 0.f, red);
    if (t == 0) ws[SLOT2_OFF + s * NBR + r] = gt2;

    // prefix of per-block jbin counts -> write base
    int cval = (t < NBR) ? (int)mh[(size_t)t * 256 + jbin] : 0;
    sh[t] = cval;
    __syncthreads();
#pragma unroll
    for (int o = 1; o < 128; o <<= 1) {
      int x = (t >= o) ? sh[t - o] : 0;
      __syncthreads();
      sh[t] += x;
      __syncthreads();
    }
    int base = (r > 0) ? sh[r - 1] : 0;

    if (t == 0) wcnt = 0u;
    __syncthreads();
    const float* ce = ws + off;
    float* cbuf = ws + CBUF_OFF + (size_t)s * CAPC;
    for (int i = r * 256 + t; i < M; i += NBR * 256) {
      float v = ce[i];
      unsigned b = __float_as_uint(v);
      if ((int)(b >> 23) == ibin && (int)((b >> 15) & 255u) == jbin) {
        unsigned idx = (unsigned)base + atomicAdd(&wcnt, 1u);
        if (idx < CAPC) cbuf[idx] = v;
      }
    }
  }

  // ---- ticket: last-arriving block per scale does the final assembly ----
  __threadfence();
  __syncthreads();
  if (t == 0) tickL = atomicAdd(&((unsigned*)(ws + TICKET_OFF))[s], 1u);
  __syncthreads();
  if (tickL != (unsigned)(NBR - 1)) return;
  __threadfence();   // acquire: make other blocks' writes visible

  float kf = stf[2], n_pos = stf[3];
  float s_ce_pos = stf[4], s_tcl_ttm = stf[5], s_tcl_negm = stf[6], s_ttm_pp = stf[7];

  float lpart = (t < NBR) ? ws[SLOTGT_OFF + s * NBR + t] : 0.f;
  float loss_neg = block_sum(lpart, red);

  if (rem > 0) {
    float l2 = (t < NBR) ? ws[SLOT2_OFF + s * NBR + t] : 0.f;
    loss_neg += block_sum(l2, red);

    int cnt = min(jcnt, CAPC);
    const float* cbuf = ws + CBUF_OFF + (size_t)s * CAPC;

    hist[t] = 0; __syncthreads();
    for (int i = t; i < cnt; i += 256)
      atomicAdd(&hist[(__float_as_uint(cbuf[i]) >> 7) & 255u], 1);
    __syncthreads();
    int h = hist[t];
    int suf = suffix_scan_256(h, sh);
    int above = suf - h;
    int remcur = rem2;
    if (suf >= remcur && above < remcur) { sel[0] = t; sel[1] = remcur - above; }
    __syncthreads();
    int b1 = sel[0]; remcur = sel[1];
    __syncthreads();

    hist[t] = 0; __syncthreads();
    for (int i = t; i < cnt; i += 256) {
      unsigned b = __float_as_uint(cbuf[i]);
      if (((b >> 7) & 255u) == (unsigned)b1) atomicAdd(&hist[b & 127u], 1);
    }
    __syncthreads();
    h = (t < 128) ? hist[t] : 0;
    suf = suffix_scan_256(h, sh);
    above = suf - h;
    if (t < 128 && suf >= remcur && above < remcur) { sel[0] = t; }
    __syncthreads();
    int lb0 = sel[0];
    __syncthreads();

    unsigned prefix = ((unsigned)ibin << 23) | ((unsigned)jbin << 15) |
                      ((unsigned)b1 << 7) | (unsigned)lb0;
    float tval = __uint_as_float(prefix);

    float sum_in = 0.f, cgt = 0.f;
    for (int i = t; i < cnt; i += 256) {
      unsigned b = __float_as_uint(cbuf[i]);
      if (b > prefix) { sum_in += cbuf[i]; cgt += 1.f; }
    }
    sum_in = block_sum(sum_in, red);
    cgt = block_sum(cgt, red);
    loss_neg += sum_in + ((float)rem2 - cgt) * tval;
  }

  if (t == 0) {
    float loss_pos = (n_pos > 0.f) ? s_ce_pos : 0.f;
    float loss_tr = (loss_pos + loss_neg) / (n_pos + kf);

    float negm = (float)M - n_pos;
    float mp = s_tcl_ttm / fmaxf(n_pos, 1.f);
    float mn = s_tcl_negm / fmaxf(negm, 1.f);
    float loss_tcl = (n_pos > 0.f) ? (mp + 0.5f * mn) : 0.f;

    float loss_ct = (n_pos > 0.f) ? (0.5f * s_ttm_pp / (n_pos * 200.f)) : 0.f;

    atomicAdd(&out[0], loss_tr);
    atomicAdd(&out[1], loss_tcl);
    atomicAdd(&out[2], loss_ct);
  }
}

extern "C" void kernel_launch(void* const* d_in, const int* in_sizes, int n_in,
                              void* d_out, int out_size, void* d_ws, size_t ws_size,
                              hipStream_t stream) {
  (void)in_sizes; (void)n_in; (void)out_size; (void)ws_size;
  const float* cls3 = (const float*)d_in[0];
  const float* reg3 = (const float*)d_in[1];
  const float* gt3  = (const float*)d_in[2];
  const float* cls4 = (const float*)d_in[3];
  const float* reg4 = (const float*)d_in[4];
  const float* gt4  = (const float*)d_in[5];
  const float* cls5 = (const float*)d_in[6];
  const float* reg5 = (const float*)d_in[7];
  const float* gt5  = (const float*)d_in[8];

  float* ws = (float*)d_ws;
  float* out = (float*)d_out;

  pixel_kernel<<<dim3(NB3 + NB4 + NB5, 4), 128, 0, stream>>>(
      cls3, reg3, gt3, cls4, reg4, gt4, cls5, reg5, gt5, ws, out);

  refine_kernel<<<dim3(NBR, 3), 256, 0, stream>>>(ws);
  compactB_kernel<<<dim3(NBR, 3), 256, 0, stream>>>(ws, out);
}

// Round 18
// 58.372 us; speedup vs baseline: 1.3645x; 1.3645x over previous
//
#include <hip/hip_runtime.h>
#include <math.h>

#define DEVI __device__ __forceinline__

static constexpr float KD[10] = {
  0.027333068345077982f,  0.029519490925774643f, -0.039134249302383094f,
  0.1993975339773936f,    0.7234076904024206f,    0.6339789634582119f,
  0.01660210576452232f,  -0.17532808990845047f,  -0.021101834024758855f,
  0.019538882735286728f};

// ---------- workspace layout (float offsets) ----------
#define CE_OFF     0         // 105000 floats
#define PH_OFF     105056    // exp-hist partials: nb x 256 uints per scale
#define PH1_REL    40192     // NB3*256
#define PH2_REL    50432     // + NB4*256
#define MH_OFF     160608    // m8-hist partials: 3 x 96 x 256 uints
#define BS_OFF     234336    // m8 bin value-sum partials: 3 x 96 x 256 floats
#define SLOTGT_OFF 308064    // 3 x 96 floats
#define STATE_OFF  308352    // 3 x 8 words
#define SLOT2_OFF  308384    // 3 x 96 floats
#define CBUF_OFF   308672    // 3 x CAPC floats (16B aligned)
#define CAPC       49152
#define PART_OFF   456128    // 3 x PART_STRIDE floats
#define PART_STRIDE 3840     // >= 4*NB3*6 = 3768

#define NB3 157              // ceil(80000/512)  (2 px/thread)
#define NB4 40               // ceil(20000/512)
#define NB5 20               // ceil(5000/256)   (1 px/thread, HW odd)
#define NBR 96

DEVI float wave_sum(float v) {
#pragma unroll
  for (int d = 32; d; d >>= 1) v += __shfl_down(v, d);
  return v;
}

DEVI float block_sum(float v, float* sh) {
  int lane = threadIdx.x & 63, wid = threadIdx.x >> 6;
  v = wave_sum(v);
  if (lane == 0) sh[wid] = v;
  __syncthreads();
  if (threadIdx.x == 0) {
    float s = 0.f;
    int nw = blockDim.x >> 6;
    for (int w = 0; w < nw; ++w) s += sh[w];
    sh[0] = s;
  }
  __syncthreads();
  float r = sh[0];
  __syncthreads();
  return r;
}

DEVI int suffix_scan_256(int v, int* sh) {
  int t = threadIdx.x;
  sh[t] = v;
  __syncthreads();
#pragma unroll
  for (int off = 1; off < 256; off <<= 1) {
    int x = (t + off < 256) ? sh[t + off] : 0;
    __syncthreads();
    sh[t] += x;
    __syncthreads();
  }
  return sh[t];
}

DEVI float sl1(float v) { float a = fabsf(v); return (a < 1.f) ? 0.5f * v * v : a - 0.5f; }

DEVI float ce2cls(float la, float lb, float tgt) {
  float m = fmaxf(la, lb);
  float lse = m + __logf(__expf(la - m) + __expf(lb - m));
  return lse - ((tgt > 0.5f) ? lb : la);
}

// ---- scalar half-recon (scale 5) ----
template <int H>
DEVI float recon_half(const float* __restrict__ rb, const float* __restrict__ gb,
                      int rc0, int gc0, size_t HW, float off) {
  constexpr int CLO  = (H == 0) ? 0 : 6;
  constexpr int A1LO = (H == 0) ? 0 : 12;
  constexpr int J2LO = (H == 0) ? 0 : 25;
  float c[14];
#pragma unroll
  for (int i = 0; i < 14; ++i)
    c[i] = rb[(size_t)(rc0 + CLO + i) * HW] - gb[(size_t)(gc0 + CLO + i) * HW];
  float a1[19];
#pragma unroll
  for (int k = 0; k < 19; ++k) {
    int o1 = A1LO + k, b = (o1 >> 1) - CLO;
    if (o1 & 1)
      a1[k] = KD[0]*c[b] + KD[2]*c[b+1] + KD[4]*c[b+2] + KD[6]*c[b+3] + KD[8]*c[b+4];
    else
      a1[k] = KD[1]*c[b] + KD[3]*c[b+1] + KD[5]*c[b+2] + KD[7]*c[b+3] + KD[9]*c[b+4];
  }
  float w0=0.f,w1=0.f,w2=0.f,w3=0.f,w4=0.f, acc=0.f;
#pragma unroll
  for (int k = 0; k < 29; ++k) {
    int j2 = J2LO + k, b = (j2 >> 1) - A1LO;
    float a2v;
    if (j2 & 1)
      a2v = KD[0]*a1[b] + KD[2]*a1[b+1] + KD[4]*a1[b+2] + KD[6]*a1[b+3] + KD[8]*a1[b+4];
    else
      a2v = KD[1]*a1[b] + KD[3]*a1[b+1] + KD[5]*a1[b+2] + KD[7]*a1[b+3] + KD[9]*a1[b+4];
    w0=w1; w1=w2; w2=w3; w3=w4; w4=a2v;
    if (k >= 4) {
      acc += sl1(KD[1]*w0 + KD[3]*w1 + KD[5]*w2 + KD[7]*w3 + KD[9]*w4 + off);
      acc += sl1(KD[0]*w0 + KD[2]*w1 + KD[4]*w2 + KD[6]*w3 + KD[8]*w4 + off);
    }
  }
  return acc;
}

// ---- float2 dual-pixel half-recon (scales 3/4, HW even, hw even) ----
DEVI float2 tap2o(const float2* a, int b) {
  float2 r;
  r.x = KD[0]*a[b].x + KD[2]*a[b+1].x + KD[4]*a[b+2].x + KD[6]*a[b+3].x + KD[8]*a[b+4].x;
  r.y = KD[0]*a[b].y + KD[2]*a[b+1].y + KD[4]*a[b+2].y + KD[6]*a[b+3].y + KD[8]*a[b+4].y;
  return r;
}
DEVI float2 tap2e(const float2* a, int b) {
  float2 r;
  r.x = KD[1]*a[b].x + KD[3]*a[b+1].x + KD[5]*a[b+2].x + KD[7]*a[b+3].x + KD[9]*a[b+4].x;
  r.y = KD[1]*a[b].y + KD[3]*a[b+1].y + KD[5]*a[b+2].y + KD[7]*a[b+3].y + KD[9]*a[b+4].y;
  return r;
}
template <int H>
DEVI float2 recon2(const float* __restrict__ rb, const float* __restrict__ gb,
                   int rc0, int gc0, size_t HW, float2 off) {
  constexpr int CLO  = (H == 0) ? 0 : 6;
  constexpr int A1LO = (H == 0) ? 0 : 12;
  constexpr int J2LO = (H == 0) ? 0 : 25;
  float2 c[14];
#pragma unroll
  for (int i = 0; i < 14; ++i) {
    float2 rv = *(const float2*)(rb + (size_t)(rc0 + CLO + i) * HW);
    float2 gv = *(const float2*)(gb + (size_t)(gc0 + CLO + i) * HW);
    c[i].x = rv.x - gv.x; c[i].y = rv.y - gv.y;
  }
  float2 a1[19];
#pragma unroll
  for (int k = 0; k < 19; ++k) {
    int o1 = A1LO + k, b = (o1 >> 1) - CLO;
    a1[k] = (o1 & 1) ? tap2o(c, b) : tap2e(c, b);
  }
  float2 w0={0,0},w1={0,0},w2={0,0},w3={0,0},w4={0,0};
  float2 acc={0,0};
#pragma unroll
  for (int k = 0; k < 29; ++k) {
    int j2 = J2LO + k, b = (j2 >> 1) - A1LO;
    float2 a2v = (j2 & 1) ? tap2o(a1, b) : tap2e(a1, b);
    w0=w1; w1=w2; w2=w3; w3=w4; w4=a2v;
    if (k >= 4) {
      float vex = KD[1]*w0.x + KD[3]*w1.x + KD[5]*w2.x + KD[7]*w3.x + KD[9]*w4.x + off.x;
      float vey = KD[1]*w0.y + KD[3]*w1.y + KD[5]*w2.y + KD[7]*w3.y + KD[9]*w4.y + off.y;
      float vox = KD[0]*w0.x + KD[2]*w1.x + KD[4]*w2.x + KD[6]*w3.x + KD[8]*w4.x + off.x;
      float voy = KD[0]*w0.y + KD[2]*w1.y + KD[4]*w2.y + KD[6]*w3.y + KD[8]*w4.y + off.y;
      acc.x += sl1(vex) + sl1(vox);
      acc.y += sl1(vey) + sl1(voy);
    }
  }
  return acc;
}

// Fused over 3 scales; blockIdx.y in [0,4): axis = y>>1, half = y&1.
// Scales 3/4: 2 px/thread via float2. Scale 5: scalar.
// (256,3): VGPR cap ~170 (fits ~150 needed) -> 3 blocks/CU vs 2.
__global__ void __launch_bounds__(256, 3)
pixel_kernel(const float* __restrict__ cls3, const float* __restrict__ reg3, const float* __restrict__ gt3,
             const float* __restrict__ cls4, const float* __restrict__ reg4, const float* __restrict__ gt4,
             const float* __restrict__ cls5, const float* __restrict__ reg5, const float* __restrict__ gt5,
             float* __restrict__ ws, float* __restrict__ out) {
  int bx = blockIdx.x, y = blockIdx.y, t = threadIdx.x;
  int axis = y >> 1, half = y & 1;
  const float *cls, *reg, *gt;
  int M, HW, ceOff, partBase, phRel, nb, lbx, two;
  if (bx < NB3) {
    cls = cls3; reg = reg3; gt = gt3; M = 80000; HW = 10000;
    ceOff = 0; partBase = PART_OFF; phRel = 0; nb = NB3; lbx = bx; two = 1;
  } else if (bx < NB3 + NB4) {
    cls = cls4; reg = reg4; gt = gt4; M = 20000; HW = 2500;
    ceOff = 80000; partBase = PART_OFF + PART_STRIDE; phRel = PH1_REL; nb = NB4; lbx = bx - NB3; two = 1;
  } else {
    cls = cls5; reg = reg5; gt = gt5; M = 5000; HW = 625;
    ceOff = 100000; partBase = PART_OFF + 2 * PART_STRIDE; phRel = PH2_REL; nb = NB5; lbx = bx - NB3 - NB4; two = 0;
  }
  float* ceArr = ws + ceOff;
  unsigned* ph = (unsigned*)(ws + PH_OFF) + phRel;

  if (bx == 0 && y == 0 && t < 3) out[t] = 0.f;

  __shared__ unsigned hlds[256];
  __shared__ float shp[4][6];
  hlds[t] = 0u;
  __syncthreads();

  float cnt_pos = 0.f, cnt_neg = 0.f, s_ce_pos = 0.f, s_tcl_ttm = 0.f, s_tcl_negm = 0.f;
  float s_ttm_pp = 0.f;
  int rc0 = axis ? 21 : 0;
  int gc0 = axis ? 24 : 3;

  if (two) {
    int p0 = (lbx * 256 + t) * 2;
    if (p0 < M) {
      int n = p0 / HW, hw = p0 % HW;      // hw even, pair stays in-row (HW even)
      const float* gb = gt  + (size_t)n * 45 * HW + hw;
      const float* rb = reg + (size_t)n * 42 * HW + hw;
      float2 trv = *(const float2*)(gb);
      float2 tnv = *(const float2*)(gb + 2 * (size_t)HW);
      float2 ttm; ttm.x = trv.x * tnv.x; ttm.y = trv.y * tnv.y;

      if (y == 0) {
        const float* cb = cls + (size_t)n * 4 * HW + hw;
        float2 l0 = *(const float2*)(cb);
        float2 l1 = *(const float2*)(cb + (size_t)HW);
        float2 l2 = *(const float2*)(cb + 2 * (size_t)HW);
        float2 l3 = *(const float2*)(cb + 3 * (size_t)HW);
        float2 tcl = *(const float2*)(gb + (size_t)HW);
        float cex = ce2cls(l0.x, l1.x, trv.x), cey = ce2cls(l0.y, l1.y, trv.y);
        float ctx = ce2cls(l2.x, l3.x, tcl.x), cty = ce2cls(l2.y, l3.y, tcl.y);
        bool posx = ttm.x > 0.f, posy = ttm.y > 0.f;
        bool negx = ((1.f - trv.x) * tnv.x) > 0.f, negy = ((1.f - trv.y) * tnv.y) > 0.f;
        float cvx = negx ? cex : 0.f, cvy = negy ? cey : 0.f;
        float2 cev; cev.x = cvx; cev.y = cvy;
        *(float2*)(ceArr + p0) = cev;
        if (negx) atomicAdd(&hlds[__float_as_uint(cvx) >> 23], 1u);
        if (negy) atomicAdd(&hlds[__float_as_uint(cvy) >> 23], 1u);
        cnt_pos = (posx ? 1.f : 0.f) + (posy ? 1.f : 0.f);
        cnt_neg = (negx ? 1.f : 0.f) + (negy ? 1.f : 0.f);
        s_ce_pos = (posx ? cex : 0.f) + (posy ? cey : 0.f);
        s_tcl_ttm = ctx * ttm.x + cty * ttm.y;
        s_tcl_negm = ctx * (1.f - ttm.x) + cty * (1.f - ttm.y);
      }

      float2 rcv = *(const float2*)(rb + (size_t)(rc0 + 20) * HW);
      float2 gcv = *(const float2*)(gb + (size_t)(gc0 + 20) * HW);
      float2 dc; dc.x = rcv.x - gcv.x; dc.y = rcv.y - gcv.y;
      float2 pp = half ? recon2<1>(rb, gb, rc0, gc0, (size_t)HW, dc)
                       : recon2<0>(rb, gb, rc0, gc0, (size_t)HW, dc);
      s_ttm_pp = ttm.x * pp.x + ttm.y * pp.y;
    }
  } else {
    int p = lbx * 256 + t;
    if (p < M) {
      int n = p / HW, hw = p % HW;
      const float* gb = gt  + (size_t)n * 45 * HW + hw;
      const float* rb = reg + (size_t)n * 42 * HW + hw;
      float tr = gb[0], train = gb[2 * (size_t)HW];
      float ttm = tr * train;
      if (y == 0) {
        const float* cb = cls + (size_t)n * 4 * HW + hw;
        float ce_tr = ce2cls(cb[0], cb[(size_t)HW], tr);
        float ce_tcl = ce2cls(cb[2 * (size_t)HW], cb[3 * (size_t)HW], gb[(size_t)HW]);
        bool pos = ttm > 0.f;
        bool neg = ((1.f - tr) * train) > 0.f;
        float cev = neg ? ce_tr : 0.f;
        ceArr[p] = cev;
        if (neg) atomicAdd(&hlds[__float_as_uint(cev) >> 23], 1u);
        cnt_pos = pos ? 1.f : 0.f;
        cnt_neg = neg ? 1.f : 0.f;
        s_ce_pos = pos ? ce_tr : 0.f;
        s_tcl_ttm = ce_tcl * ttm;
        s_tcl_negm = ce_tcl * (1.f - ttm);
      }
      float dc = rb[(size_t)(rc0 + 20) * HW] - gb[(size_t)(gc0 + 20) * HW];
      float pp = half ? recon_half<1>(rb, gb, rc0, gc0, (size_t)HW, dc)
                      : recon_half<0>(rb, gb, rc0, gc0, (size_t)HW, dc);
      s_ttm_pp = ttm * pp;
    }
  }

  int lane = t & 63, wid = t >> 6;
  cnt_pos = wave_sum(cnt_pos);
  cnt_neg = wave_sum(cnt_neg);
  s_ce_pos = wave_sum(s_ce_pos);
  s_tcl_ttm = wave_sum(s_tcl_ttm);
  s_tcl_negm = wave_sum(s_tcl_negm);
  s_ttm_pp = wave_sum(s_ttm_pp);
  if (lane == 0) {
    shp[wid][0] = cnt_pos; shp[wid][1] = cnt_neg; shp[wid][2] = s_ce_pos;
    shp[wid][3] = s_tcl_ttm; shp[wid][4] = s_tcl_negm; shp[wid][5] = s_ttm_pp;
  }
  __syncthreads();
  if (t < 6) {
    float s = shp[0][t] + shp[1][t] + shp[2][t] + shp[3][t];
    ws[partBase + (size_t)(y * nb + lbx) * 6 + t] = s;
  }
  if (y == 0)
    ph[(size_t)lbx * 256 + t] = hlds[t];
}

// grid-wide refine with MERGED selA: every block redundantly computes
// (ibin, rem) via atomic-free PH sweep; r==0 writes STATE. Then the ce scan.
__global__ void refine_kernel(float* __restrict__ ws) {
  int s = blockIdx.y, r = blockIdx.x, t = threadIdx.x;
  int M   = (s == 0) ? 80000 : (s == 1 ? 20000 : 5000);
  int off = (s == 0) ? 0     : (s == 1 ? 80000 : 100000);
  int nb0 = (s == 0) ? NB3   : (s == 1 ? NB4   : NB5);
  int phRel = (s == 0) ? 0 : (s == 1 ? PH1_REL : PH2_REL);
  int* st = (int*)(ws + STATE_OFF) + s * 8;

  __shared__ int sh[256];
  __shared__ int sel[2];
  __shared__ float red[4];
  __shared__ unsigned hW[4][256];
  __shared__ unsigned mhL[256];
  __shared__ float bsL[256];

  const float* part = ws + PART_OFF + s * PART_STRIDE;
  int npart = 4 * nb0;
  float a0 = 0.f, a1 = 0.f, a2 = 0.f, a3 = 0.f, a4 = 0.f, a5 = 0.f;
  for (int i = t; i < npart; i += 256) {
    const float* p6 = part + (size_t)i * 6;
    a0 += p6[0]; a1 += p6[1]; a2 += p6[2]; a3 += p6[3]; a4 += p6[4]; a5 += p6[5];
  }
  a0 = block_sum(a0, red);
  a1 = block_sum(a1, red);
  a2 = block_sum(a2, red);
  a3 = block_sum(a3, red);
  a4 = block_sum(a4, red);
  a5 = block_sum(a5, red);

  float cnt_pos = a0, cnt_negf = a1;
  int cnt_neg = (int)cnt_negf;
  float kf = (cnt_pos > 0.f) ? fminf(cnt_negf, floorf(3.f * cnt_pos)) : 100.f;
  int k_take = min((int)kf, cnt_neg);

  int ibin, rem;
  if (k_take >= cnt_neg) { ibin = -1; rem = 0; }
  else if (k_take <= 0)  { ibin = 256; rem = 0; }
  else {
    const uint4* ph4 = (const uint4*)((const unsigned*)(ws + PH_OFF) + phRel);
    unsigned c0 = 0u, c1 = 0u, c2 = 0u, c3 = 0u;
    int n4 = nb0 * 64;
    for (int i = t; i < n4; i += 256) {
      uint4 u = ph4[i];
      c0 += u.x; c1 += u.y; c2 += u.z; c3 += u.w;
    }
    int wid = t >> 6, b0 = (4 * t) & 255;
    hW[wid][b0 + 0] = c0; hW[wid][b0 + 1] = c1; hW[wid][b0 + 2] = c2; hW[wid][b0 + 3] = c3;
    __syncthreads();
    int h = (int)(hW[0][t] + hW[1][t] + hW[2][t] + hW[3][t]);
    int suf = suffix_scan_256(h, sh);
    int above = suf - h;
    if (suf >= k_take && above < k_take) { sel[0] = t; sel[1] = k_take - above; }
    __syncthreads();
    ibin = sel[0]; rem = sel[1];
    __syncthreads();
  }
  if (r == 0 && t == 0) {
    st[0] = ibin; st[1] = rem;
    float* stf = (float*)st;
    stf[2] = kf; stf[3] = a0; stf[4] = a2; stf[5] = a3; stf[6] = a4; stf[7] = a5;
  }

  mhL[t] = 0u; bsL[t] = 0.f;
  __syncthreads();
  const float* ce = ws + off;
  float sum = 0.f;
  for (int i = r * 256 + t; i < M; i += NBR * 256) {
    float v = ce[i];
    unsigned b = __float_as_uint(v);
    int e = (int)(b >> 23);
    if (e > ibin) sum += v;
    else if (e == ibin && rem > 0) {
      int m8 = (int)((b >> 15) & 255u);
      atomicAdd(&mhL[m8], 1u);
      atomicAdd(&bsL[m8], v);
    }
  }
  sum = block_sum(sum, red);
  if (t == 0) ws[SLOTGT_OFF + s * NBR + r] = sum;
  if (rem > 0) {
    ((unsigned*)(ws + MH_OFF))[((size_t)s * NBR + r) * 256 + t] = mhL[t];
    ws[BS_OFF + ((size_t)s * NBR + r) * 256 + t] = bsL[t];
  }
}

// grid-wide: redundant jbin select (atomic-free MH sweep); per-block gt2 from
// OWN bs row; prefix of per-block jbin counts -> contention-free rank-write
__global__ void compactB_kernel(float* __restrict__ ws) {
  int s = blockIdx.y, r = blockIdx.x, t = threadIdx.x;
  int M   = (s == 0) ? 80000 : (s == 1 ? 20000 : 5000);
  int off = (s == 0) ? 0     : (s == 1 ? 80000 : 100000);
  const int* st = (const int*)(ws + STATE_OFF) + s * 8;
  int ibin = st[0], rem = st[1];
  if (rem <= 0) return;

  __shared__ int sh[256];
  __shared__ int sel[2];
  __shared__ float red[4];
  __shared__ unsigned hW[4][256];
  __shared__ unsigned wcnt;

  const unsigned* mh = (const unsigned*)(ws + MH_OFF) + (size_t)s * NBR * 256;
  const uint4* mh4 = (const uint4*)mh;
  unsigned c0 = 0u, c1 = 0u, c2 = 0u, c3 = 0u;
  for (int i = t; i < NBR * 64; i += 256) {
    uint4 u = mh4[i];
    c0 += u.x; c1 += u.y; c2 += u.z; c3 += u.w;
  }
  int wid = t >> 6, b0 = (4 * t) & 255;
  hW[wid][b0 + 0] = c0; hW[wid][b0 + 1] = c1; hW[wid][b0 + 2] = c2; hW[wid][b0 + 3] = c3;
  __syncthreads();
  int h = (int)(hW[0][t] + hW[1][t] + hW[2][t] + hW[3][t]);
  int suf = suffix_scan_256(h, sh);
  int above = suf - h;
  if (suf >= rem && above < rem) { sel[0] = t; }
  __syncthreads();
  int jbin = sel[0];
  __syncthreads();

  float v2 = ws[BS_OFF + ((size_t)s * NBR + r) * 256 + t];
  float gt2 = block_sum((t > jbin) ? v2 : 0.f, red);
  if (t == 0) ws[SLOT2_OFF + s * NBR + r] = gt2;

  int cval = (t < NBR) ? (int)mh[(size_t)t * 256 + jbin] : 0;
  sh[t] = cval;
  __syncthreads();
#pragma unroll
  for (int o = 1; o < 128; o <<= 1) {
    int x = (t >= o) ? sh[t - o] : 0;
    __syncthreads();
    sh[t] += x;
    __syncthreads();
  }
  int base = (r > 0) ? sh[r - 1] : 0;

  if (t == 0) wcnt = 0u;
  __syncthreads();
  const float* ce = ws + off;
  float* cbuf = ws + CBUF_OFF + (size_t)s * CAPC;
  for (int i = r * 256 + t; i < M; i += NBR * 256) {
    float v = ce[i];
    unsigned b = __float_as_uint(v);
    if ((int)(b >> 23) == ibin && (int)((b >> 15) & 255u) == jbin) {
      unsigned idx = (unsigned)base + atomicAdd(&wcnt, 1u);
      if (idx < CAPC) cbuf[idx] = v;
    }
  }
}

// one block per scale: atomic-free MH sweep -> (jbin, rem2, jcnt);
// loss_neg = sum(SLOTGT)+sum(SLOT2)+radix over cbuf; assemble losses.
__global__ void final_kernel(float* __restrict__ ws, float* __restrict__ out) {
  int s = blockIdx.x, t = threadIdx.x;
  int M = (s == 0) ? 80000 : (s == 1 ? 20000 : 5000);
  const int* st = (const int*)(ws + STATE_OFF) + s * 8;
  const float* stf = (const float*)st;

  __shared__ int sh[256];
  __shared__ int sel[2];
  __shared__ float red[4];
  __shared__ unsigned hW[4][256];
  __shared__ int hist[256];

  int ibin = st[0], rem = st[1];
  float kf = stf[2], n_pos = stf[3];
  float s_ce_pos = stf[4], s_tcl_ttm = stf[5], s_tcl_negm = stf[6], s_ttm_pp = stf[7];

  float lpart = (t < NBR) ? ws[SLOTGT_OFF + s * NBR + t] : 0.f;
  float loss_neg = block_sum(lpart, red);

  if (rem > 0) {
    const uint4* mh4 = (const uint4*)((const unsigned*)(ws + MH_OFF) + (size_t)s * NBR * 256);
    unsigned c0 = 0u, c1 = 0u, c2 = 0u, c3 = 0u;
    for (int i = t; i < NBR * 64; i += 256) {
      uint4 u = mh4[i];
      c0 += u.x; c1 += u.y; c2 += u.z; c3 += u.w;
    }
    int wid = t >> 6, b0 = (4 * t) & 255;
    hW[wid][b0 + 0] = c0; hW[wid][b0 + 1] = c1; hW[wid][b0 + 2] = c2; hW[wid][b0 + 3] = c3;
    __syncthreads();
    int h = (int)(hW[0][t] + hW[1][t] + hW[2][t] + hW[3][t]);
    int suf = suffix_scan_256(h, sh);
    int above = suf - h;
    if (suf >= rem && above < rem) { sel[0] = t; sel[1] = rem - above; }
    __syncthreads();
    int jbin = sel[0], rem2 = sel[1];
    int jcnt = (int)(hW[0][jbin] + hW[1][jbin] + hW[2][jbin] + hW[3][jbin]);
    __syncthreads();

    float l2 = (t < NBR) ? ws[SLOT2_OFF + s * NBR + t] : 0.f;
    loss_neg += block_sum(l2, red);

    int cnt = min(jcnt, CAPC);
    const float* cbuf = ws + CBUF_OFF + (size_t)s * CAPC;

    hist[t] = 0; __syncthreads();
    for (int i = t; i < cnt; i += 256)
      atomicAdd(&hist[(__float_as_uint(cbuf[i]) >> 7) & 255u], 1);
    __syncthreads();
    h = hist[t];
    suf = suffix_scan_256(h, sh);
    above = suf - h;
    int remcur = rem2;
    if (suf >= remcur && above < remcur) { sel[0] = t; sel[1] = remcur - above; }
    __syncthreads();
    int b1 = sel[0]; remcur = sel[1];
    __syncthreads();

    hist[t] = 0; __syncthreads();
    for (int i = t; i < cnt; i += 256) {
      unsigned b = __float_as_uint(cbuf[i]);
      if (((b >> 7) & 255u) == (unsigned)b1) atomicAdd(&hist[b & 127u], 1);
    }
    __syncthreads();
    h = (t < 128) ? hist[t] : 0;
    suf = suffix_scan_256(h, sh);
    above = suf - h;
    if (t < 128 && suf >= remcur && above < remcur) { sel[0] = t; }
    __syncthreads();
    int lb0 = sel[0];
    __syncthreads();

    unsigned prefix = ((unsigned)ibin << 23) | ((unsigned)jbin << 15) |
                      ((unsigned)b1 << 7) | (unsigned)lb0;
    float tval = __uint_as_float(prefix);

    float sum_in = 0.f, cgt = 0.f;
    for (int i = t; i < cnt; i += 256) {
      unsigned b = __float_as_uint(cbuf[i]);
      if (b > prefix) { sum_in += cbuf[i]; cgt += 1.f; }
    }
    sum_in = block_sum(sum_in, red);
    cgt = block_sum(cgt, red);
    loss_neg += sum_in + ((float)rem2 - cgt) * tval;
  }

  if (t == 0) {
    float loss_pos = (n_pos > 0.f) ? s_ce_pos : 0.f;
    float loss_tr = (loss_pos + loss_neg) / (n_pos + kf);

    float negm = (float)M - n_pos;
    float mp = s_tcl_ttm / fmaxf(n_pos, 1.f);
    float mn = s_tcl_negm / fmaxf(negm, 1.f);
    float loss_tcl = (n_pos > 0.f) ? (mp + 0.5f * mn) : 0.f;

    float loss_ct = (n_pos > 0.f) ? (0.5f * s_ttm_pp / (n_pos * 200.f)) : 0.f;

    atomicAdd(&out[0], loss_tr);
    atomicAdd(&out[1], loss_tcl);
    atomicAdd(&out[2], loss_ct);
  }
}

extern "C" void kernel_launch(void* const* d_in, const int* in_sizes, int n_in,
                              void* d_out, int out_size, void* d_ws, size_t ws_size,
                              hipStream_t stream) {
  (void)in_sizes; (void)n_in; (void)out_size; (void)ws_size;
  const float* cls3 = (const float*)d_in[0];
  const float* reg3 = (const float*)d_in[1];
  const float* gt3  = (const float*)d_in[2];
  const float* cls4 = (const float*)d_in[3];
  const float* reg4 = (const float*)d_in[4];
  const float* gt4  = (const float*)d_in[5];
  const float* cls5 = (const float*)d_in[6];
  const float* reg5 = (const float*)d_in[7];
  const float* gt5  = (const float*)d_in[8];

  float* ws = (float*)d_ws;
  float* out = (float*)d_out;

  pixel_kernel<<<dim3(NB3 + NB4 + NB5, 4), 256, 0, stream>>>(
      cls3, reg3, gt3, cls4, reg4, gt4, cls5, reg5, gt5, ws, out);

  refine_kernel<<<dim3(NBR, 3), 256, 0, stream>>>(ws);
  compactB_kernel<<<dim3(NBR, 3), 256, 0, stream>>>(ws);
  final_kernel<<<3, 256, 0, stream>>>(ws, out);
}